// Round 1
// baseline (733.644 us; speedup 1.0000x reference)
//
#include <hip/hip_runtime.h>

// Problem constants (fixed by setup_inputs)
#define N0_ 3514368
#define T0_ 135168
#define T1_ 12288
#define F0_ 25
#define F1_ 10
#define D_  100
#define H_  256
#define C_  128
#define IC_ 4096

// ---------------------------------------------------------------------------
// K1: neigh0[i,:] = mean_j x_feat[col0[i,j],:]   (T0 x 100)
// One wave per row; lane covers feature lane and (lane+64 if <100).
// HBM-bound: ~1.35 GB of random 400B row reads.
// ---------------------------------------------------------------------------
__global__ __launch_bounds__(256) void k1_gather(const float* __restrict__ xf,
                                                 const int* __restrict__ col0,
                                                 float* __restrict__ neigh0) {
    const int lane = threadIdx.x & 63;
    const int row  = blockIdx.x * 4 + (threadIdx.x >> 6);
    int myidx = 0;
    if (lane < F0_) myidx = col0[row * F0_ + lane];
    float acc0 = 0.f, acc1 = 0.f;
#pragma unroll
    for (int j = 0; j < F0_; ++j) {
        int s = __shfl(myidx, j, 64);
        const float* rp = xf + (size_t)s * D_;
        acc0 += rp[lane];
        if (lane < D_ - 64) acc1 += rp[64 + lane];
    }
    const float inv = 1.0f / F0_;
    neigh0[(size_t)row * D_ + lane] = acc0 * inv;
    if (lane < D_ - 64) neigh0[(size_t)row * D_ + 64 + lane] = acc1 * inv;
}

// ---------------------------------------------------------------------------
// K2: h = relu(neigh0 @ Wn0 + x_feat[:T0] @ Ws0 + b0)   (T0 x 256)
// 32 rows/block, 256 threads; thread t owns output column t for all 32 rows.
// A-tiles in LDS (broadcast float4 reads), weights streamed from L1/L2.
// ---------------------------------------------------------------------------
__global__ __launch_bounds__(256) void k2_layer0(const float* __restrict__ neigh0,
                                                 const float* __restrict__ xf,
                                                 const float* __restrict__ Wn0,
                                                 const float* __restrict__ Ws0,
                                                 const float* __restrict__ b0,
                                                 float* __restrict__ h) {
    __shared__ __align__(16) float An[32 * D_];
    __shared__ __align__(16) float Ax[32 * D_];
    const int t = threadIdx.x;
    const int base = blockIdx.x * 32;

    for (int k = t; k < 32 * D_; k += 256) {
        int r = k / D_;
        int d = k - r * D_;
        An[k] = neigh0[(size_t)(base + r) * D_ + d];
        Ax[k] = xf[(size_t)(base + r) * D_ + d];
    }
    __syncthreads();

    float acc[32];
    const float bias = b0[t];
#pragma unroll
    for (int r = 0; r < 32; ++r) acc[r] = bias;

    // neigh0 @ Wn0
    for (int d4 = 0; d4 < D_ / 4; ++d4) {
        const int d = d4 * 4;
        const float w0 = Wn0[(d + 0) * H_ + t];
        const float w1 = Wn0[(d + 1) * H_ + t];
        const float w2 = Wn0[(d + 2) * H_ + t];
        const float w3 = Wn0[(d + 3) * H_ + t];
#pragma unroll
        for (int r = 0; r < 32; ++r) {
            float4 a = *reinterpret_cast<const float4*>(&An[r * D_ + d]);
            acc[r] += a.x * w0 + a.y * w1 + a.z * w2 + a.w * w3;
        }
    }
    // x_feat @ Ws0
    for (int d4 = 0; d4 < D_ / 4; ++d4) {
        const int d = d4 * 4;
        const float w0 = Ws0[(d + 0) * H_ + t];
        const float w1 = Ws0[(d + 1) * H_ + t];
        const float w2 = Ws0[(d + 2) * H_ + t];
        const float w3 = Ws0[(d + 3) * H_ + t];
#pragma unroll
        for (int r = 0; r < 32; ++r) {
            float4 a = *reinterpret_cast<const float4*>(&Ax[r * D_ + d]);
            acc[r] += a.x * w0 + a.y * w1 + a.z * w2 + a.w * w3;
        }
    }
#pragma unroll
    for (int r = 0; r < 32; ++r) {
        float v = acc[r];
        h[(size_t)(base + r) * H_ + t] = v > 0.f ? v : 0.f;
    }
}

// ---------------------------------------------------------------------------
// K3: out_u = (mean_j h[col1]) @ Wn1 + h[:T1] @ Ws1 + b1   (T1 x 128), no relu
// 16 rows/block, 256 threads. Gather phase: thread t = feature t (256 = H).
// GEMM phase: 2 groups of 128 threads; each thread 8 rows x 1 col.
// ---------------------------------------------------------------------------
__global__ __launch_bounds__(256) void k3_layer1(const float* __restrict__ h,
                                                 const int* __restrict__ col1,
                                                 const float* __restrict__ Wn1,
                                                 const float* __restrict__ Ws1,
                                                 const float* __restrict__ b1,
                                                 float* __restrict__ out_u) {
    __shared__ __align__(16) float Ng[16 * H_];
    __shared__ __align__(16) float Sf[16 * H_];
    const int t = threadIdx.x;
    const int base = blockIdx.x * 16;

    for (int r = 0; r < 16; ++r) {
        float a = 0.f;
#pragma unroll
        for (int j = 0; j < F1_; ++j) {
            int idx = col1[(base + r) * F1_ + j];
            a += h[(size_t)idx * H_ + t];
        }
        Ng[r * H_ + t] = a * (1.0f / F1_);
        Sf[r * H_ + t] = h[(size_t)(base + r) * H_ + t];
    }
    __syncthreads();

    const int c  = t & (C_ - 1);
    const int rg = t >> 7;  // 0 or 1: rows rg*8 .. rg*8+7
    float acc[8];
    const float bias = b1[c];
#pragma unroll
    for (int r8 = 0; r8 < 8; ++r8) acc[r8] = bias;

    for (int d4 = 0; d4 < H_ / 4; ++d4) {
        const int d = d4 * 4;
        const float wn0_ = Wn1[(d + 0) * C_ + c];
        const float wn1_ = Wn1[(d + 1) * C_ + c];
        const float wn2_ = Wn1[(d + 2) * C_ + c];
        const float wn3_ = Wn1[(d + 3) * C_ + c];
        const float ws0_ = Ws1[(d + 0) * C_ + c];
        const float ws1_ = Ws1[(d + 1) * C_ + c];
        const float ws2_ = Ws1[(d + 2) * C_ + c];
        const float ws3_ = Ws1[(d + 3) * C_ + c];
#pragma unroll
        for (int r8 = 0; r8 < 8; ++r8) {
            const int r = rg * 8 + r8;
            float4 n = *reinterpret_cast<const float4*>(&Ng[r * H_ + d]);
            float4 s = *reinterpret_cast<const float4*>(&Sf[r * H_ + d]);
            acc[r8] += n.x * wn0_ + n.y * wn1_ + n.z * wn2_ + n.w * wn3_
                     + s.x * ws0_ + s.y * ws1_ + s.z * ws2_ + s.w * ws3_;
        }
    }
#pragma unroll
    for (int r8 = 0; r8 < 8; ++r8)
        out_u[(size_t)(base + rg * 8 + r8) * C_ + c] = acc[r8];
}

// ---------------------------------------------------------------------------
// K4: edge scores. 32 edges/block, 256 threads.
// edge j: src = rm[j & 4095], dst = rm[4096 + j]
// e = src_row * dst_row; scores = relu(e@Wp1+bp1)@Wp2 + bp2
// ---------------------------------------------------------------------------
__global__ __launch_bounds__(256) void k4_edges(const float* __restrict__ out_u,
                                                const int* __restrict__ rmap,
                                                const float* __restrict__ Wp1,
                                                const float* __restrict__ bp1,
                                                const float* __restrict__ Wp2,
                                                const float* __restrict__ bp2,
                                                float* __restrict__ scores) {
    __shared__ __align__(16) float E[32 * C_];
    const int t = threadIdx.x;
    const int base = blockIdx.x * 32;
    const int f = t & 127;
    const int half = t >> 7;

    for (int rr = 0; rr < 16; ++rr) {
        const int row = rr * 2 + half;
        const int j = base + row;
        const int si = rmap[j & (IC_ - 1)];
        const int di = rmap[IC_ + j];
        E[row * C_ + f] = out_u[(size_t)si * C_ + f] * out_u[(size_t)di * C_ + f];
    }
    __syncthreads();

    // phase A: t1 = relu(E @ Wp1 + bp1); thread: col f, rows half*16..+15
    float acc[16];
    const float bias = bp1[f];
#pragma unroll
    for (int r16 = 0; r16 < 16; ++r16) acc[r16] = bias;

    for (int d4 = 0; d4 < C_ / 4; ++d4) {
        const int d = d4 * 4;
        const float w0 = Wp1[(d + 0) * C_ + f];
        const float w1 = Wp1[(d + 1) * C_ + f];
        const float w2 = Wp1[(d + 2) * C_ + f];
        const float w3 = Wp1[(d + 3) * C_ + f];
#pragma unroll
        for (int r16 = 0; r16 < 16; ++r16) {
            const int r = half * 16 + r16;
            float4 e4 = *reinterpret_cast<const float4*>(&E[r * C_ + d]);
            acc[r16] += e4.x * w0 + e4.y * w1 + e4.z * w2 + e4.w * w3;
        }
    }
    __syncthreads();
#pragma unroll
    for (int r16 = 0; r16 < 16; ++r16) {
        float v = acc[r16];
        E[(half * 16 + r16) * C_ + f] = v > 0.f ? v : 0.f;
    }
    __syncthreads();

    // phase B: score[r] = sum_c t1[r][c] * Wp2[c] + bp2
    const int r = t >> 3;
    const int s = t & 7;
    float p = 0.f;
#pragma unroll
    for (int k4 = 0; k4 < 4; ++k4) {
        float4 tv = *reinterpret_cast<const float4*>(&E[r * C_ + s * 16 + k4 * 4]);
        float4 wv = *reinterpret_cast<const float4*>(&Wp2[s * 16 + k4 * 4]);
        p += tv.x * wv.x + tv.y * wv.y + tv.z * wv.z + tv.w * wv.w;
    }
    p += __shfl_down(p, 4, 8);
    p += __shfl_down(p, 2, 8);
    p += __shfl_down(p, 1, 8);
    if (s == 0) scores[base + r] = p + bp2[0];
}

// ---------------------------------------------------------------------------
extern "C" void kernel_launch(void* const* d_in, const int* in_sizes, int n_in,
                              void* d_out, int out_size, void* d_ws, size_t ws_size,
                              hipStream_t stream) {
    const float* xf   = (const float*)d_in[0];
    const float* Wn0  = (const float*)d_in[1];
    const float* Ws0  = (const float*)d_in[2];
    const float* b0   = (const float*)d_in[3];
    const float* Wn1  = (const float*)d_in[4];
    const float* Ws1  = (const float*)d_in[5];
    const float* b1   = (const float*)d_in[6];
    const float* Wp1  = (const float*)d_in[7];
    const float* bp1  = (const float*)d_in[8];
    const float* Wp2  = (const float*)d_in[9];
    const float* bp2  = (const float*)d_in[10];
    const int*   col0 = (const int*)d_in[11];
    const int*   col1 = (const int*)d_in[12];
    const int*   rmap = (const int*)d_in[13];
    // d_in[14] = id_count scalar (compile-time IC_ = 4096)

    float* ws     = (float*)d_ws;
    float* neigh0 = ws;                                   // T0 * 100  (54.1 MB)
    float* h      = neigh0 + (size_t)T0_ * D_;            // T0 * 256  (138.4 MB)
    float* out_u  = h + (size_t)T0_ * H_;                 // T1 * 128  (6.3 MB)
    float* scores = (float*)d_out;                        // 8192

    hipLaunchKernelGGL(k1_gather, dim3(T0_ / 4), dim3(256), 0, stream, xf, col0, neigh0);
    hipLaunchKernelGGL(k2_layer0, dim3(T0_ / 32), dim3(256), 0, stream,
                       neigh0, xf, Wn0, Ws0, b0, h);
    hipLaunchKernelGGL(k3_layer1, dim3(T1_ / 16), dim3(256), 0, stream,
                       h, col1, Wn1, Ws1, b1, out_u);
    hipLaunchKernelGGL(k4_edges, dim3((2 * IC_) / 32), dim3(256), 0, stream,
                       out_u, rmap, Wp1, bp1, Wp2, bp2, scores);
}

// Round 2
// 609.567 us; speedup vs baseline: 1.2035x; 1.2035x over previous
//
#include <hip/hip_runtime.h>
#include <hip/hip_bf16.h>

// Problem constants (fixed by setup_inputs)
#define N0_ 3514368
#define T0_ 135168
#define T1_ 12288
#define F0_ 25
#define F1_ 10
#define D_  100
#define H_  256
#define C_  128
#define IC_ 4096

// Packed-fragment geometry for layer-0 MFMA GEMM (16x16x32 bf16):
//   A rows = T0, K = 256 padded (k 0-127: neigh0 feats 0-99 + pad, k 128-255: self feats + pad)
//   rb = row/16 (8448), ks = 0..7, part = 0(hi)/1(lo)
//   Apk[(((rb*8+ks)*2+part)*64 + lane)*8 + j]  (bf16 as ushort)
//   lane holds A[row = rb*16 + (lane&15)][k = ks*32 + (lane>>4)*8 + j]
//   Wpk same for B: lane holds W[k][n = nb*16 + (lane&15)], nb = 0..15
#define RB_ (T0_ / 16)

typedef __attribute__((ext_vector_type(8))) short bf8_t;   // 8 bf16 in 4 VGPRs
typedef __attribute__((ext_vector_type(4))) float f4_t;

__device__ inline void split_bf16(float v, ushort& hi, ushort& lo) {
    __hip_bfloat16 hb = __float2bfloat16(v);
    float hf = __bfloat162float(hb);
    __hip_bfloat16 lb = __float2bfloat16(v - hf);
    hi = *reinterpret_cast<ushort*>(&hb);
    lo = *reinterpret_cast<ushort*>(&lb);
}

// ---------------------------------------------------------------------------
// K0: pack Wn0|Ws0 (each 100x256 f32, row-major [k][n]) into Wpk fragments.
// 16 blocks x 256 thr; tiny (400 KB in, 512 KB out).
// ---------------------------------------------------------------------------
__global__ __launch_bounds__(256) void k0_packW(const float* __restrict__ Wn0,
                                                const float* __restrict__ Ws0,
                                                ushort* __restrict__ Wpk) {
    const int nb = blockIdx.x;           // 0..15
    for (int it = 0; it < 4; ++it) {
        const int task = threadIdx.x + it * 256;   // 0..1023 = ks(8) x part(2) x lane(64)
        const int ks   = task >> 7;
        const int part = (task >> 6) & 1;
        const int lane = task & 63;
        const int n  = nb * 16 + (lane & 15);
        const int kb = (ks & 3) * 32 + (lane >> 4) * 8;
        const float* src = (ks < 4) ? Wn0 : Ws0;
        ushort out[8];
#pragma unroll
        for (int j = 0; j < 8; ++j) {
            const int k = kb + j;
            float v = (k < D_) ? src[k * H_ + n] : 0.f;
            ushort hi, lo;
            split_bf16(v, hi, lo);
            out[j] = part ? lo : hi;
        }
        ushort* dst = Wpk + ((size_t)((nb * 8 + ks) * 2 + part) * 64 + lane) * 8;
        *reinterpret_cast<bf8_t*>(dst) = *reinterpret_cast<bf8_t*>(out);
    }
}

// ---------------------------------------------------------------------------
// K1: gather-mean (neigh0) + self rows -> packed split-bf16 A fragments.
// One block = 16 rows (one rb). 4 waves x 4 rows each. ~1.9 GB HBM (dominant).
// ---------------------------------------------------------------------------
__global__ __launch_bounds__(256) void k1_gather_pack(const float* __restrict__ xf,
                                                      const int* __restrict__ col0,
                                                      ushort* __restrict__ Apk) {
    __shared__ float rowN[16][D_];
    __shared__ float rowS[16][D_];
    const int lane = threadIdx.x & 63;
    const int wid  = threadIdx.x >> 6;
    const int rb   = blockIdx.x;

    // phase 1: gather-mean 4 rows per wave + self rows
#pragma unroll
    for (int i = 0; i < 4; ++i) {
        const int r   = wid * 4 + i;            // 0..15 within block
        const int row = rb * 16 + r;
        int myidx = 0;
        if (lane < F0_) myidx = col0[row * F0_ + lane];
        float acc0 = 0.f, acc1 = 0.f;
#pragma unroll
        for (int j = 0; j < F0_; ++j) {
            const int s = __shfl(myidx, j, 64);
            const float* rp = xf + (size_t)s * D_;
            acc0 += rp[lane];
            if (lane < D_ - 64) acc1 += rp[64 + lane];
        }
        const float inv = 1.0f / F0_;
        rowN[r][lane] = acc0 * inv;
        if (lane < D_ - 64) rowN[r][64 + lane] = acc1 * inv;
        // self row
        const float* sp = xf + (size_t)row * D_;
        rowS[r][lane] = sp[lane];
        if (lane < D_ - 64) rowS[r][64 + lane] = sp[64 + lane];
    }
    __syncthreads();

    // phase 2: pack into fragment layout. 512 (ks,part,lane) tasks over 256 thr,
    // each task writes neigh region (ks) and self region (ks+4).
#pragma unroll
    for (int it = 0; it < 2; ++it) {
        const int task = threadIdx.x + it * 256;  // ks(0..3) x part(2) x lane(64)
        const int ks   = task >> 7;
        const int part = (task >> 6) & 1;
        const int ln   = task & 63;
        const int r    = ln & 15;
        const int kb   = ks * 32 + (ln >> 4) * 8;
        ushort outN[8], outS[8];
#pragma unroll
        for (int j = 0; j < 8; ++j) {
            const int k = kb + j;
            const float vN = (k < D_) ? rowN[r][k] : 0.f;
            const float vS = (k < D_) ? rowS[r][k] : 0.f;
            ushort hi, lo;
            split_bf16(vN, hi, lo);
            outN[j] = part ? lo : hi;
            split_bf16(vS, hi, lo);
            outS[j] = part ? lo : hi;
        }
        ushort* dN = Apk + ((size_t)(((size_t)rb * 8 + ks) * 2 + part) * 64 + ln) * 8;
        ushort* dS = Apk + ((size_t)(((size_t)rb * 8 + (ks + 4)) * 2 + part) * 64 + ln) * 8;
        *reinterpret_cast<bf8_t*>(dN) = *reinterpret_cast<bf8_t*>(outN);
        *reinterpret_cast<bf8_t*>(dS) = *reinterpret_cast<bf8_t*>(outS);
    }
}

// ---------------------------------------------------------------------------
// K2: h = relu(A @ Wcat + b0) via split-bf16 MFMA. No LDS, no barriers.
// Block = 64 rows x 256 cols; 4 waves, wave w = 64 rows x cols [w*64, w*64+64).
// Per wave: 8 ksteps x {16 coalesced 1KB loads + 48 MFMA}.
// ---------------------------------------------------------------------------
__global__ __launch_bounds__(256) void k2_mfma(const ushort* __restrict__ Apk,
                                               const ushort* __restrict__ Wpk,
                                               const float* __restrict__ b0,
                                               float* __restrict__ h) {
    const int lane = threadIdx.x & 63;
    const int wid  = threadIdx.x >> 6;
    const int rb0  = blockIdx.x * 4;   // 4 row-frags
    const int nb0  = wid * 4;          // 4 col-frags

    f4_t acc[4][4] = {};

#pragma unroll
    for (int ks = 0; ks < 8; ++ks) {
        bf8_t ah[4], al[4], bh[4], bl[4];
#pragma unroll
        for (int ri = 0; ri < 4; ++ri) {
            const ushort* p = Apk + ((size_t)(((size_t)(rb0 + ri) * 8 + ks) * 2) * 64 + lane) * 8;
            ah[ri] = *reinterpret_cast<const bf8_t*>(p);
            al[ri] = *reinterpret_cast<const bf8_t*>(p + 512);
        }
#pragma unroll
        for (int ci = 0; ci < 4; ++ci) {
            const ushort* p = Wpk + ((size_t)(((nb0 + ci) * 8 + ks) * 2) * 64 + lane) * 8;
            bh[ci] = *reinterpret_cast<const bf8_t*>(p);
            bl[ci] = *reinterpret_cast<const bf8_t*>(p + 512);
        }
#pragma unroll
        for (int ri = 0; ri < 4; ++ri)
#pragma unroll
            for (int ci = 0; ci < 4; ++ci) {
                acc[ri][ci] = __builtin_amdgcn_mfma_f32_16x16x32_bf16(ah[ri], bh[ci], acc[ri][ci], 0, 0, 0);
                acc[ri][ci] = __builtin_amdgcn_mfma_f32_16x16x32_bf16(ah[ri], bl[ci], acc[ri][ci], 0, 0, 0);
                acc[ri][ci] = __builtin_amdgcn_mfma_f32_16x16x32_bf16(al[ri], bh[ci], acc[ri][ci], 0, 0, 0);
            }
    }

    // epilogue: C/D layout col = lane&15, row = (lane>>4)*4 + q  [m89-verified]
    const int col_in = lane & 15;
    const int rgrp   = lane >> 4;
#pragma unroll
    for (int ci = 0; ci < 4; ++ci) {
        const int n = (nb0 + ci) * 16 + col_in;
        const float bias = b0[n];
#pragma unroll
        for (int ri = 0; ri < 4; ++ri) {
            const int rowb = blockIdx.x * 64 + ri * 16 + rgrp * 4;
#pragma unroll
            for (int q = 0; q < 4; ++q) {
                float v = acc[ri][ci][q] + bias;
                h[(size_t)(rowb + q) * H_ + n] = v > 0.f ? v : 0.f;
            }
        }
    }
}

// ---------------------------------------------------------------------------
// K3: out_u = (mean_j h[col1]) @ Wn1 + h[:T1] @ Ws1 + b1   (T1 x 128)
// ---------------------------------------------------------------------------
__global__ __launch_bounds__(256) void k3_layer1(const float* __restrict__ h,
                                                 const int* __restrict__ col1,
                                                 const float* __restrict__ Wn1,
                                                 const float* __restrict__ Ws1,
                                                 const float* __restrict__ b1,
                                                 float* __restrict__ out_u) {
    __shared__ __align__(16) float Ng[16 * H_];
    __shared__ __align__(16) float Sf[16 * H_];
    const int t = threadIdx.x;
    const int base = blockIdx.x * 16;

    for (int r = 0; r < 16; ++r) {
        float a = 0.f;
#pragma unroll
        for (int j = 0; j < F1_; ++j) {
            int idx = col1[(base + r) * F1_ + j];
            a += h[(size_t)idx * H_ + t];
        }
        Ng[r * H_ + t] = a * (1.0f / F1_);
        Sf[r * H_ + t] = h[(size_t)(base + r) * H_ + t];
    }
    __syncthreads();

    const int c  = t & (C_ - 1);
    const int rg = t >> 7;
    float acc[8];
    const float bias = b1[c];
#pragma unroll
    for (int r8 = 0; r8 < 8; ++r8) acc[r8] = bias;

    for (int d4 = 0; d4 < H_ / 4; ++d4) {
        const int d = d4 * 4;
        const float wn0_ = Wn1[(d + 0) * C_ + c];
        const float wn1_ = Wn1[(d + 1) * C_ + c];
        const float wn2_ = Wn1[(d + 2) * C_ + c];
        const float wn3_ = Wn1[(d + 3) * C_ + c];
        const float ws0_ = Ws1[(d + 0) * C_ + c];
        const float ws1_ = Ws1[(d + 1) * C_ + c];
        const float ws2_ = Ws1[(d + 2) * C_ + c];
        const float ws3_ = Ws1[(d + 3) * C_ + c];
#pragma unroll
        for (int r8 = 0; r8 < 8; ++r8) {
            const int r = rg * 8 + r8;
            float4 n = *reinterpret_cast<const float4*>(&Ng[r * H_ + d]);
            float4 s = *reinterpret_cast<const float4*>(&Sf[r * H_ + d]);
            acc[r8] += n.x * wn0_ + n.y * wn1_ + n.z * wn2_ + n.w * wn3_
                     + s.x * ws0_ + s.y * ws1_ + s.z * ws2_ + s.w * ws3_;
        }
    }
#pragma unroll
    for (int r8 = 0; r8 < 8; ++r8)
        out_u[(size_t)(base + rg * 8 + r8) * C_ + c] = acc[r8];
}

// ---------------------------------------------------------------------------
// K4: edge scores (8192 edges)
// ---------------------------------------------------------------------------
__global__ __launch_bounds__(256) void k4_edges(const float* __restrict__ out_u,
                                                const int* __restrict__ rmap,
                                                const float* __restrict__ Wp1,
                                                const float* __restrict__ bp1,
                                                const float* __restrict__ Wp2,
                                                const float* __restrict__ bp2,
                                                float* __restrict__ scores) {
    __shared__ __align__(16) float E[32 * C_];
    const int t = threadIdx.x;
    const int base = blockIdx.x * 32;
    const int f = t & 127;
    const int half = t >> 7;

    for (int rr = 0; rr < 16; ++rr) {
        const int row = rr * 2 + half;
        const int j = base + row;
        const int si = rmap[j & (IC_ - 1)];
        const int di = rmap[IC_ + j];
        E[row * C_ + f] = out_u[(size_t)si * C_ + f] * out_u[(size_t)di * C_ + f];
    }
    __syncthreads();

    float acc[16];
    const float bias = bp1[f];
#pragma unroll
    for (int r16 = 0; r16 < 16; ++r16) acc[r16] = bias;

    for (int d4 = 0; d4 < C_ / 4; ++d4) {
        const int d = d4 * 4;
        const float w0 = Wp1[(d + 0) * C_ + f];
        const float w1 = Wp1[(d + 1) * C_ + f];
        const float w2 = Wp1[(d + 2) * C_ + f];
        const float w3 = Wp1[(d + 3) * C_ + f];
#pragma unroll
        for (int r16 = 0; r16 < 16; ++r16) {
            const int r = half * 16 + r16;
            float4 e4 = *reinterpret_cast<const float4*>(&E[r * C_ + d]);
            acc[r16] += e4.x * w0 + e4.y * w1 + e4.z * w2 + e4.w * w3;
        }
    }
    __syncthreads();
#pragma unroll
    for (int r16 = 0; r16 < 16; ++r16) {
        float v = acc[r16];
        E[(half * 16 + r16) * C_ + f] = v > 0.f ? v : 0.f;
    }
    __syncthreads();

    const int r = t >> 3;
    const int s = t & 7;
    float p = 0.f;
#pragma unroll
    for (int k4 = 0; k4 < 4; ++k4) {
        float4 tv = *reinterpret_cast<const float4*>(&E[r * C_ + s * 16 + k4 * 4]);
        float4 wv = *reinterpret_cast<const float4*>(&Wp2[s * 16 + k4 * 4]);
        p += tv.x * wv.x + tv.y * wv.y + tv.z * wv.z + tv.w * wv.w;
    }
    p += __shfl_down(p, 4, 8);
    p += __shfl_down(p, 2, 8);
    p += __shfl_down(p, 1, 8);
    if (s == 0) scores[base + r] = p + bp2[0];
}

// ---------------------------------------------------------------------------
extern "C" void kernel_launch(void* const* d_in, const int* in_sizes, int n_in,
                              void* d_out, int out_size, void* d_ws, size_t ws_size,
                              hipStream_t stream) {
    const float* xf   = (const float*)d_in[0];
    const float* Wn0  = (const float*)d_in[1];
    const float* Ws0  = (const float*)d_in[2];
    const float* b0   = (const float*)d_in[3];
    const float* Wn1  = (const float*)d_in[4];
    const float* Ws1  = (const float*)d_in[5];
    const float* b1   = (const float*)d_in[6];
    const float* Wp1  = (const float*)d_in[7];
    const float* bp1  = (const float*)d_in[8];
    const float* Wp2  = (const float*)d_in[9];
    const float* bp2  = (const float*)d_in[10];
    const int*   col0 = (const int*)d_in[11];
    const int*   col1 = (const int*)d_in[12];
    const int*   rmap = (const int*)d_in[13];

    // workspace layout
    char* ws = (char*)d_ws;
    ushort* Apk = (ushort*)ws;                                  // 138,412,032 B
    float*  h   = (float*)(ws + (size_t)RB_ * 8 * 2 * 64 * 8 * 2);
    float*  out_u = h + (size_t)T0_ * H_;                       // 6.3 MB
    ushort* Wpk = (ushort*)(out_u + (size_t)T1_ * C_);          // 512 KB
    float*  scores = (float*)d_out;

    hipLaunchKernelGGL(k0_packW, dim3(16), dim3(256), 0, stream, Wn0, Ws0, Wpk);
    hipLaunchKernelGGL(k1_gather_pack, dim3(RB_), dim3(256), 0, stream, xf, col0, Apk);
    hipLaunchKernelGGL(k2_mfma, dim3(T0_ / 64), dim3(256), 0, stream, Apk, Wpk, b0, h);
    hipLaunchKernelGGL(k3_layer1, dim3(T1_ / 16), dim3(256), 0, stream,
                       h, col1, Wn1, Ws1, b1, out_u);
    hipLaunchKernelGGL(k4_edges, dim3((2 * IC_) / 32), dim3(256), 0, stream,
                       out_u, rmap, Wp1, bp1, Wp2, bp2, scores);
}

// Round 3
// 466.180 us; speedup vs baseline: 1.5737x; 1.3076x over previous
//
#include <hip/hip_runtime.h>
#include <hip/hip_bf16.h>

// Problem constants (fixed by setup_inputs)
#define N0_ 3514368
#define T0_ 135168
#define T1_ 12288
#define F0_ 25
#define F1_ 10
#define D_  100
#define H_  256
#define C_  128
#define IC_ 4096

// Fragment geometry (16x16x32 bf16 MFMA), verified passing in R2:
//   A: lane holds A[row = 16*rb + (lane&15)][k = ks*32 + (lane>>4)*8 + j]
//   B: lane holds W[k][n = 16*nb + (lane&15)], same k mapping
//   C: col = lane&15, row = (lane>>4)*4 + q
// K = 256: ks 0..3 = neigh feats (0..99, zero-padded), ks 4..7 = self feats.

typedef __attribute__((ext_vector_type(8))) short bf8_t;   // 8 bf16 in 4 VGPRs
typedef __attribute__((ext_vector_type(4))) float f4_t;

__device__ inline void split_bf16(float v, ushort& hi, ushort& lo) {
    __hip_bfloat16 hb = __float2bfloat16(v);
    float hf = __bfloat162float(hb);
    __hip_bfloat16 lb = __float2bfloat16(v - hf);
    hi = *reinterpret_cast<ushort*>(&hb);
    lo = *reinterpret_cast<ushort*>(&lb);
}

// ---------------------------------------------------------------------------
// K0: pack Wn0|Ws0 (each 100x256 f32 [k][n]) into split-bf16 B fragments.
// ---------------------------------------------------------------------------
__global__ __launch_bounds__(256) void k0_packW(const float* __restrict__ Wn0,
                                                const float* __restrict__ Ws0,
                                                ushort* __restrict__ Wpk) {
    const int nb = blockIdx.x;           // 0..15
    for (int it = 0; it < 4; ++it) {
        const int task = threadIdx.x + it * 256;   // ks(8) x part(2) x lane(64)
        const int ks   = task >> 7;
        const int part = (task >> 6) & 1;
        const int lane = task & 63;
        const int n  = nb * 16 + (lane & 15);
        const int kb = (ks & 3) * 32 + (lane >> 4) * 8;
        const float* src = (ks < 4) ? Wn0 : Ws0;
        ushort out[8];
#pragma unroll
        for (int j = 0; j < 8; ++j) {
            const int k = kb + j;
            float v = (k < D_) ? src[k * H_ + n] : 0.f;
            ushort hi, lo;
            split_bf16(v, hi, lo);
            out[j] = part ? lo : hi;
        }
        ushort* dst = Wpk + ((size_t)((nb * 8 + ks) * 2 + part) * 64 + lane) * 8;
        *reinterpret_cast<bf8_t*>(dst) = *reinterpret_cast<bf8_t*>(out);
    }
}

// ---------------------------------------------------------------------------
// K12: fused gather-mean + pack + split-bf16 MFMA GEMM + bias + relu.
// Block = 256 thr = 4 waves = 64 rows. Wave w gathers rows w*16..w*16+15
// straight into fragment-layout registers, packs to LDS (64 KB), then
// computes cols [w*64, w*64+64) for all 64 rows. B (Wpk) streams from L2.
// ---------------------------------------------------------------------------
__global__ __launch_bounds__(256) void k12_fused(const float* __restrict__ xf,
                                                 const int* __restrict__ col0,
                                                 const ushort* __restrict__ Wpk,
                                                 const float* __restrict__ b0,
                                                 float* __restrict__ h) {
    __shared__ ushort Afr[4][8][2][512];   // [rb][ks][part][lane*8+j] = 64 KB
    const int lane = threadIdx.x & 63;
    const int wid  = threadIdx.x >> 6;
    const int r    = lane & 15;            // row within the wave's 16-row frag
    const int kg   = lane >> 4;            // k-group (0..3)
    const size_t row = (size_t)blockIdx.x * 64 + wid * 16 + r;

    // ---- gather phase: accumulate neighbor mean in fragment layout ----
    float accN[4][8];
    float accS[4][8];
#pragma unroll
    for (int ks = 0; ks < 4; ++ks)
#pragma unroll
        for (int j = 0; j < 8; ++j) { accN[ks][j] = 0.f; accS[ks][j] = 0.f; }

    const int* cp = col0 + row * F0_;
#pragma unroll 5
    for (int jn = 0; jn < F0_; ++jn) {
        const float* rp = xf + (size_t)cp[jn] * D_;
#pragma unroll
        for (int ks = 0; ks < 3; ++ks) {
            float4 a = *reinterpret_cast<const float4*>(rp + ks * 32 + kg * 8);
            float4 b = *reinterpret_cast<const float4*>(rp + ks * 32 + kg * 8 + 4);
            accN[ks][0] += a.x; accN[ks][1] += a.y; accN[ks][2] += a.z; accN[ks][3] += a.w;
            accN[ks][4] += b.x; accN[ks][5] += b.y; accN[ks][6] += b.z; accN[ks][7] += b.w;
        }
        if (kg == 0) {   // k = 96..99 only
            float4 a = *reinterpret_cast<const float4*>(rp + 96);
            accN[3][0] += a.x; accN[3][1] += a.y; accN[3][2] += a.z; accN[3][3] += a.w;
        }
    }
    // self row
    {
        const float* rp = xf + row * D_;
#pragma unroll
        for (int ks = 0; ks < 3; ++ks) {
            float4 a = *reinterpret_cast<const float4*>(rp + ks * 32 + kg * 8);
            float4 b = *reinterpret_cast<const float4*>(rp + ks * 32 + kg * 8 + 4);
            accS[ks][0] = a.x; accS[ks][1] = a.y; accS[ks][2] = a.z; accS[ks][3] = a.w;
            accS[ks][4] = b.x; accS[ks][5] = b.y; accS[ks][6] = b.z; accS[ks][7] = b.w;
        }
        if (kg == 0) {
            float4 a = *reinterpret_cast<const float4*>(rp + 96);
            accS[3][0] = a.x; accS[3][1] = a.y; accS[3][2] = a.z; accS[3][3] = a.w;
        }
    }

    // ---- pack phase: split-bf16 -> LDS fragments ----
    const float inv = 1.0f / F0_;
#pragma unroll
    for (int ks = 0; ks < 4; ++ks) {
        bf8_t hN, lN, hS, lS;
#pragma unroll
        for (int j = 0; j < 8; ++j) {
            ushort hi, lo;
            split_bf16(accN[ks][j] * inv, hi, lo);
            hN[j] = (short)hi; lN[j] = (short)lo;
            split_bf16(accS[ks][j], hi, lo);
            hS[j] = (short)hi; lS[j] = (short)lo;
        }
        *reinterpret_cast<bf8_t*>(&Afr[wid][ks    ][0][lane * 8]) = hN;
        *reinterpret_cast<bf8_t*>(&Afr[wid][ks    ][1][lane * 8]) = lN;
        *reinterpret_cast<bf8_t*>(&Afr[wid][ks + 4][0][lane * 8]) = hS;
        *reinterpret_cast<bf8_t*>(&Afr[wid][ks + 4][1][lane * 8]) = lS;
    }
    __syncthreads();

    // ---- MFMA phase: wave w -> cols [w*64, w*64+64) for all 64 rows ----
    const int nb0 = wid * 4;
    f4_t acc[4][4] = {};
#pragma unroll
    for (int ks = 0; ks < 8; ++ks) {
        bf8_t ah[4], al[4], bh[4], bl[4];
#pragma unroll
        for (int rb = 0; rb < 4; ++rb) {
            ah[rb] = *reinterpret_cast<const bf8_t*>(&Afr[rb][ks][0][lane * 8]);
            al[rb] = *reinterpret_cast<const bf8_t*>(&Afr[rb][ks][1][lane * 8]);
        }
#pragma unroll
        for (int ci = 0; ci < 4; ++ci) {
            const ushort* p = Wpk + ((size_t)(((nb0 + ci) * 8 + ks) * 2) * 64 + lane) * 8;
            bh[ci] = *reinterpret_cast<const bf8_t*>(p);
            bl[ci] = *reinterpret_cast<const bf8_t*>(p + 512);
        }
#pragma unroll
        for (int rb = 0; rb < 4; ++rb)
#pragma unroll
            for (int ci = 0; ci < 4; ++ci) {
                acc[rb][ci] = __builtin_amdgcn_mfma_f32_16x16x32_bf16(ah[rb], bh[ci], acc[rb][ci], 0, 0, 0);
                acc[rb][ci] = __builtin_amdgcn_mfma_f32_16x16x32_bf16(ah[rb], bl[ci], acc[rb][ci], 0, 0, 0);
                acc[rb][ci] = __builtin_amdgcn_mfma_f32_16x16x32_bf16(al[rb], bh[ci], acc[rb][ci], 0, 0, 0);
            }
    }

    // ---- epilogue: bias + relu + store ----
    const int col_in = lane & 15;
    const int rgrp   = lane >> 4;
#pragma unroll
    for (int ci = 0; ci < 4; ++ci) {
        const int n = (nb0 + ci) * 16 + col_in;
        const float bias = b0[n];
#pragma unroll
        for (int rb = 0; rb < 4; ++rb) {
            const size_t rowb = (size_t)blockIdx.x * 64 + rb * 16 + rgrp * 4;
#pragma unroll
            for (int q = 0; q < 4; ++q) {
                float v = acc[rb][ci][q] + bias;
                h[(rowb + q) * H_ + n] = v > 0.f ? v : 0.f;
            }
        }
    }
}

// ---------------------------------------------------------------------------
// K3: out_u = (mean_j h[col1]) @ Wn1 + h[:T1] @ Ws1 + b1   (T1 x 128)
// ---------------------------------------------------------------------------
__global__ __launch_bounds__(256) void k3_layer1(const float* __restrict__ h,
                                                 const int* __restrict__ col1,
                                                 const float* __restrict__ Wn1,
                                                 const float* __restrict__ Ws1,
                                                 const float* __restrict__ b1,
                                                 float* __restrict__ out_u) {
    __shared__ __align__(16) float Ng[16 * H_];
    __shared__ __align__(16) float Sf[16 * H_];
    const int t = threadIdx.x;
    const int base = blockIdx.x * 16;

    for (int r = 0; r < 16; ++r) {
        float a = 0.f;
#pragma unroll
        for (int j = 0; j < F1_; ++j) {
            int idx = col1[(base + r) * F1_ + j];
            a += h[(size_t)idx * H_ + t];
        }
        Ng[r * H_ + t] = a * (1.0f / F1_);
        Sf[r * H_ + t] = h[(size_t)(base + r) * H_ + t];
    }
    __syncthreads();

    const int c  = t & (C_ - 1);
    const int rg = t >> 7;
    float acc[8];
    const float bias = b1[c];
#pragma unroll
    for (int r8 = 0; r8 < 8; ++r8) acc[r8] = bias;

    for (int d4 = 0; d4 < H_ / 4; ++d4) {
        const int d = d4 * 4;
        const float wn0_ = Wn1[(d + 0) * C_ + c];
        const float wn1_ = Wn1[(d + 1) * C_ + c];
        const float wn2_ = Wn1[(d + 2) * C_ + c];
        const float wn3_ = Wn1[(d + 3) * C_ + c];
        const float ws0_ = Ws1[(d + 0) * C_ + c];
        const float ws1_ = Ws1[(d + 1) * C_ + c];
        const float ws2_ = Ws1[(d + 2) * C_ + c];
        const float ws3_ = Ws1[(d + 3) * C_ + c];
#pragma unroll
        for (int r8 = 0; r8 < 8; ++r8) {
            const int r = rg * 8 + r8;
            float4 n = *reinterpret_cast<const float4*>(&Ng[r * H_ + d]);
            float4 s = *reinterpret_cast<const float4*>(&Sf[r * H_ + d]);
            acc[r8] += n.x * wn0_ + n.y * wn1_ + n.z * wn2_ + n.w * wn3_
                     + s.x * ws0_ + s.y * ws1_ + s.z * ws2_ + s.w * ws3_;
        }
    }
#pragma unroll
    for (int r8 = 0; r8 < 8; ++r8)
        out_u[(size_t)(base + rg * 8 + r8) * C_ + c] = acc[r8];
}

// ---------------------------------------------------------------------------
// K4: edge scores (8192 edges)
// ---------------------------------------------------------------------------
__global__ __launch_bounds__(256) void k4_edges(const float* __restrict__ out_u,
                                                const int* __restrict__ rmap,
                                                const float* __restrict__ Wp1,
                                                const float* __restrict__ bp1,
                                                const float* __restrict__ Wp2,
                                                const float* __restrict__ bp2,
                                                float* __restrict__ scores) {
    __shared__ __align__(16) float E[32 * C_];
    const int t = threadIdx.x;
    const int base = blockIdx.x * 32;
    const int f = t & 127;
    const int half = t >> 7;

    for (int rr = 0; rr < 16; ++rr) {
        const int row = rr * 2 + half;
        const int j = base + row;
        const int si = rmap[j & (IC_ - 1)];
        const int di = rmap[IC_ + j];
        E[row * C_ + f] = out_u[(size_t)si * C_ + f] * out_u[(size_t)di * C_ + f];
    }
    __syncthreads();

    float acc[16];
    const float bias = bp1[f];
#pragma unroll
    for (int r16 = 0; r16 < 16; ++r16) acc[r16] = bias;

    for (int d4 = 0; d4 < C_ / 4; ++d4) {
        const int d = d4 * 4;
        const float w0 = Wp1[(d + 0) * C_ + f];
        const float w1 = Wp1[(d + 1) * C_ + f];
        const float w2 = Wp1[(d + 2) * C_ + f];
        const float w3 = Wp1[(d + 3) * C_ + f];
#pragma unroll
        for (int r16 = 0; r16 < 16; ++r16) {
            const int r = half * 16 + r16;
            float4 e4 = *reinterpret_cast<const float4*>(&E[r * C_ + d]);
            acc[r16] += e4.x * w0 + e4.y * w1 + e4.z * w2 + e4.w * w3;
        }
    }
    __syncthreads();
#pragma unroll
    for (int r16 = 0; r16 < 16; ++r16) {
        float v = acc[r16];
        E[(half * 16 + r16) * C_ + f] = v > 0.f ? v : 0.f;
    }
    __syncthreads();

    const int r = t >> 3;
    const int s = t & 7;
    float p = 0.f;
#pragma unroll
    for (int k4 = 0; k4 < 4; ++k4) {
        float4 tv = *reinterpret_cast<const float4*>(&E[r * C_ + s * 16 + k4 * 4]);
        float4 wv = *reinterpret_cast<const float4*>(&Wp2[s * 16 + k4 * 4]);
        p += tv.x * wv.x + tv.y * wv.y + tv.z * wv.z + tv.w * wv.w;
    }
    p += __shfl_down(p, 4, 8);
    p += __shfl_down(p, 2, 8);
    p += __shfl_down(p, 1, 8);
    if (s == 0) scores[base + r] = p + bp2[0];
}

// ---------------------------------------------------------------------------
extern "C" void kernel_launch(void* const* d_in, const int* in_sizes, int n_in,
                              void* d_out, int out_size, void* d_ws, size_t ws_size,
                              hipStream_t stream) {
    const float* xf   = (const float*)d_in[0];
    const float* Wn0  = (const float*)d_in[1];
    const float* Ws0  = (const float*)d_in[2];
    const float* b0   = (const float*)d_in[3];
    const float* Wn1  = (const float*)d_in[4];
    const float* Ws1  = (const float*)d_in[5];
    const float* b1   = (const float*)d_in[6];
    const float* Wp1  = (const float*)d_in[7];
    const float* bp1  = (const float*)d_in[8];
    const float* Wp2  = (const float*)d_in[9];
    const float* bp2  = (const float*)d_in[10];
    const int*   col0 = (const int*)d_in[11];
    const int*   col1 = (const int*)d_in[12];
    const int*   rmap = (const int*)d_in[13];

    // workspace layout
    char* ws = (char*)d_ws;
    float*  h     = (float*)ws;                                 // T0*256 f32 = 138.4 MB
    float*  out_u = h + (size_t)T0_ * H_;                       // T1*128 f32 = 6.3 MB
    ushort* Wpk   = (ushort*)(out_u + (size_t)T1_ * C_);        // 512 KB
    float*  scores = (float*)d_out;

    hipLaunchKernelGGL(k0_packW, dim3(16), dim3(256), 0, stream, Wn0, Ws0, Wpk);
    hipLaunchKernelGGL(k12_fused, dim3(T0_ / 64), dim3(256), 0, stream,
                       xf, col0, Wpk, b0, h);
    hipLaunchKernelGGL(k3_layer1, dim3(T1_ / 16), dim3(256), 0, stream,
                       h, col1, Wn1, Ws1, b1, out_u);
    hipLaunchKernelGGL(k4_edges, dim3((2 * IC_) / 32), dim3(256), 0, stream,
                       out_u, rmap, Wp1, bp1, Wp2, bp2, scores);
}

// Round 4
// 401.997 us; speedup vs baseline: 1.8250x; 1.1597x over previous
//
#include <hip/hip_runtime.h>
#include <hip/hip_bf16.h>

// Problem constants (fixed by setup_inputs)
#define N0_ 3514368
#define T0_ 135168
#define T1_ 12288
#define F0_ 25
#define F1_ 10
#define D_  100
#define H_  256
#define C_  128
#define IC_ 4096

// Fragment geometry (16x16x32 bf16 MFMA), HW-verified in R2/R3:
//   A: lane holds A[row = 16*rb + (lane&15)][k = ks*32 + (lane>>4)*8 + j]
//   B: lane holds W[k][n = 16*nb + (lane&15)], same k mapping
//   C: col = lane&15, row = (lane>>4)*4 + q
// K = 256: ks 0..3 = neigh feats (0..99 zero-padded), ks 4..7 = self feats.

typedef __attribute__((ext_vector_type(8))) short bf8_t;
typedef __attribute__((ext_vector_type(4))) float f4_t;

__device__ inline void split_bf16(float v, ushort& hi, ushort& lo) {
    __hip_bfloat16 hb = __float2bfloat16(v);
    float hf = __bfloat162float(hb);
    __hip_bfloat16 lb = __float2bfloat16(v - hf);
    hi = *reinterpret_cast<ushort*>(&hb);
    lo = *reinterpret_cast<ushort*>(&lb);
}

// ---------------------------------------------------------------------------
// Bz: zero the needed-row flags (T0 bytes = 33792 dwords).
// ---------------------------------------------------------------------------
__global__ __launch_bounds__(256) void bz_zero(unsigned int* __restrict__ flag32) {
    const int i = blockIdx.x * 256 + threadIdx.x;
    if (i < T0_ / 4) flag32[i] = 0u;
}

// ---------------------------------------------------------------------------
// Bs: set flags for rows referenced by layer 1: unique(col1) U [0,T1).
// Racy same-value byte writes -> deterministic.
// ---------------------------------------------------------------------------
__global__ __launch_bounds__(256) void bs_set(const int* __restrict__ col1,
                                              unsigned char* __restrict__ flag) {
    const int i = blockIdx.x * 256 + threadIdx.x;
    if (i < T1_ * F1_) flag[col1[i]] = 1;
    if (i < T1_) flag[i] = 1;
}

// ---------------------------------------------------------------------------
// K0: pack Wn0|Ws0 (each 100x256 f32 [k][n]) into split-bf16 B fragments.
// ---------------------------------------------------------------------------
__global__ __launch_bounds__(256) void k0_packW(const float* __restrict__ Wn0,
                                                const float* __restrict__ Ws0,
                                                ushort* __restrict__ Wpk) {
    const int nb = blockIdx.x;           // 0..15
    for (int it = 0; it < 4; ++it) {
        const int task = threadIdx.x + it * 256;   // ks(8) x part(2) x lane(64)
        const int ks   = task >> 7;
        const int part = (task >> 6) & 1;
        const int lane = task & 63;
        const int n  = nb * 16 + (lane & 15);
        const int kb = (ks & 3) * 32 + (lane >> 4) * 8;
        const float* src = (ks < 4) ? Wn0 : Ws0;
        ushort out[8];
#pragma unroll
        for (int j = 0; j < 8; ++j) {
            const int k = kb + j;
            float v = (k < D_) ? src[k * H_ + n] : 0.f;
            ushort hi, lo;
            split_bf16(v, hi, lo);
            out[j] = part ? lo : hi;
        }
        ushort* dst = Wpk + ((size_t)((nb * 8 + ks) * 2 + part) * 64 + lane) * 8;
        *reinterpret_cast<bf8_t*>(dst) = *reinterpret_cast<bf8_t*>(out);
    }
}

// ---------------------------------------------------------------------------
// K12: fused gather-mean + pack + split-bf16 MFMA + bias + relu, with
// dead-row elimination: rows whose h is never read skip all loads/stores.
// ---------------------------------------------------------------------------
__global__ __launch_bounds__(256) void k12_fused(const float* __restrict__ xf,
                                                 const int* __restrict__ col0,
                                                 const ushort* __restrict__ Wpk,
                                                 const float* __restrict__ b0,
                                                 const unsigned char* __restrict__ flag,
                                                 float* __restrict__ h) {
    __shared__ ushort Afr[4][8][2][512];   // [rb][ks][part][lane*8+j] = 64 KB
    const int lane = threadIdx.x & 63;
    const int wid  = threadIdx.x >> 6;
    const int r    = lane & 15;
    const int kg   = lane >> 4;
    const size_t row = (size_t)blockIdx.x * 64 + wid * 16 + r;
    const bool needed = (flag[row] != 0);

    // ---- gather phase (predicated on needed) ----
    float accN[4][8];
    float accS[4][8];
#pragma unroll
    for (int ks = 0; ks < 4; ++ks)
#pragma unroll
        for (int j = 0; j < 8; ++j) { accN[ks][j] = 0.f; accS[ks][j] = 0.f; }

    if (needed) {
        const int* cp = col0 + row * F0_;
#pragma unroll 5
        for (int jn = 0; jn < F0_; ++jn) {
            const float* rp = xf + (size_t)cp[jn] * D_;
#pragma unroll
            for (int ks = 0; ks < 3; ++ks) {
                float4 a = *reinterpret_cast<const float4*>(rp + ks * 32 + kg * 8);
                float4 b = *reinterpret_cast<const float4*>(rp + ks * 32 + kg * 8 + 4);
                accN[ks][0] += a.x; accN[ks][1] += a.y; accN[ks][2] += a.z; accN[ks][3] += a.w;
                accN[ks][4] += b.x; accN[ks][5] += b.y; accN[ks][6] += b.z; accN[ks][7] += b.w;
            }
            if (kg == 0) {
                float4 a = *reinterpret_cast<const float4*>(rp + 96);
                accN[3][0] += a.x; accN[3][1] += a.y; accN[3][2] += a.z; accN[3][3] += a.w;
            }
        }
        const float* rp = xf + row * D_;
#pragma unroll
        for (int ks = 0; ks < 3; ++ks) {
            float4 a = *reinterpret_cast<const float4*>(rp + ks * 32 + kg * 8);
            float4 b = *reinterpret_cast<const float4*>(rp + ks * 32 + kg * 8 + 4);
            accS[ks][0] = a.x; accS[ks][1] = a.y; accS[ks][2] = a.z; accS[ks][3] = a.w;
            accS[ks][4] = b.x; accS[ks][5] = b.y; accS[ks][6] = b.z; accS[ks][7] = b.w;
        }
        if (kg == 0) {
            float4 a = *reinterpret_cast<const float4*>(rp + 96);
            accS[3][0] = a.x; accS[3][1] = a.y; accS[3][2] = a.z; accS[3][3] = a.w;
        }
    }

    // ---- pack phase: split-bf16 -> LDS fragments ----
    const float inv = 1.0f / F0_;
#pragma unroll
    for (int ks = 0; ks < 4; ++ks) {
        bf8_t hN, lN, hS, lS;
#pragma unroll
        for (int j = 0; j < 8; ++j) {
            ushort hi, lo;
            split_bf16(accN[ks][j] * inv, hi, lo);
            hN[j] = (short)hi; lN[j] = (short)lo;
            split_bf16(accS[ks][j], hi, lo);
            hS[j] = (short)hi; lS[j] = (short)lo;
        }
        *reinterpret_cast<bf8_t*>(&Afr[wid][ks    ][0][lane * 8]) = hN;
        *reinterpret_cast<bf8_t*>(&Afr[wid][ks    ][1][lane * 8]) = lN;
        *reinterpret_cast<bf8_t*>(&Afr[wid][ks + 4][0][lane * 8]) = hS;
        *reinterpret_cast<bf8_t*>(&Afr[wid][ks + 4][1][lane * 8]) = lS;
    }
    __syncthreads();

    // ---- MFMA phase: wave w -> cols [w*64, w*64+64) for all 64 rows ----
    const int nb0 = wid * 4;
    f4_t acc[4][4] = {};
#pragma unroll
    for (int ks = 0; ks < 8; ++ks) {
        bf8_t ah[4], al[4], bh[4], bl[4];
#pragma unroll
        for (int rb = 0; rb < 4; ++rb) {
            ah[rb] = *reinterpret_cast<const bf8_t*>(&Afr[rb][ks][0][lane * 8]);
            al[rb] = *reinterpret_cast<const bf8_t*>(&Afr[rb][ks][1][lane * 8]);
        }
#pragma unroll
        for (int ci = 0; ci < 4; ++ci) {
            const ushort* p = Wpk + ((size_t)(((nb0 + ci) * 8 + ks) * 2) * 64 + lane) * 8;
            bh[ci] = *reinterpret_cast<const bf8_t*>(p);
            bl[ci] = *reinterpret_cast<const bf8_t*>(p + 512);
        }
#pragma unroll
        for (int rb = 0; rb < 4; ++rb)
#pragma unroll
            for (int ci = 0; ci < 4; ++ci) {
                acc[rb][ci] = __builtin_amdgcn_mfma_f32_16x16x32_bf16(ah[rb], bh[ci], acc[rb][ci], 0, 0, 0);
                acc[rb][ci] = __builtin_amdgcn_mfma_f32_16x16x32_bf16(ah[rb], bl[ci], acc[rb][ci], 0, 0, 0);
                acc[rb][ci] = __builtin_amdgcn_mfma_f32_16x16x32_bf16(al[rb], bh[ci], acc[rb][ci], 0, 0, 0);
            }
    }

    // ---- epilogue: bias + relu + store (only needed rows) ----
    const int col_in = lane & 15;
    const int rgrp   = lane >> 4;
    bool vflag[4][4];
#pragma unroll
    for (int rb = 0; rb < 4; ++rb)
#pragma unroll
        for (int q = 0; q < 4; ++q)
            vflag[rb][q] = (flag[(size_t)blockIdx.x * 64 + rb * 16 + rgrp * 4 + q] != 0);
#pragma unroll
    for (int ci = 0; ci < 4; ++ci) {
        const int n = (nb0 + ci) * 16 + col_in;
        const float bias = b0[n];
#pragma unroll
        for (int rb = 0; rb < 4; ++rb) {
            const size_t rowb = (size_t)blockIdx.x * 64 + rb * 16 + rgrp * 4;
#pragma unroll
            for (int q = 0; q < 4; ++q) {
                if (vflag[rb][q]) {
                    float v = acc[rb][ci][q] + bias;
                    h[(rowb + q) * H_ + n] = v > 0.f ? v : 0.f;
                }
            }
        }
    }
}

// ---------------------------------------------------------------------------
// K3: out_u = (mean_j h[col1]) @ Wn1 + h[:T1] @ Ws1 + b1   (T1 x 128)
// ---------------------------------------------------------------------------
__global__ __launch_bounds__(256) void k3_layer1(const float* __restrict__ h,
                                                 const int* __restrict__ col1,
                                                 const float* __restrict__ Wn1,
                                                 const float* __restrict__ Ws1,
                                                 const float* __restrict__ b1,
                                                 float* __restrict__ out_u) {
    __shared__ __align__(16) float Ng[16 * H_];
    __shared__ __align__(16) float Sf[16 * H_];
    const int t = threadIdx.x;
    const int base = blockIdx.x * 16;

    for (int r = 0; r < 16; ++r) {
        float a = 0.f;
#pragma unroll
        for (int j = 0; j < F1_; ++j) {
            int idx = col1[(base + r) * F1_ + j];
            a += h[(size_t)idx * H_ + t];
        }
        Ng[r * H_ + t] = a * (1.0f / F1_);
        Sf[r * H_ + t] = h[(size_t)(base + r) * H_ + t];
    }
    __syncthreads();

    const int c  = t & (C_ - 1);
    const int rg = t >> 7;
    float acc[8];
    const float bias = b1[c];
#pragma unroll
    for (int r8 = 0; r8 < 8; ++r8) acc[r8] = bias;

    for (int d4 = 0; d4 < H_ / 4; ++d4) {
        const int d = d4 * 4;
        const float wn0_ = Wn1[(d + 0) * C_ + c];
        const float wn1_ = Wn1[(d + 1) * C_ + c];
        const float wn2_ = Wn1[(d + 2) * C_ + c];
        const float wn3_ = Wn1[(d + 3) * C_ + c];
        const float ws0_ = Ws1[(d + 0) * C_ + c];
        const float ws1_ = Ws1[(d + 1) * C_ + c];
        const float ws2_ = Ws1[(d + 2) * C_ + c];
        const float ws3_ = Ws1[(d + 3) * C_ + c];
#pragma unroll
        for (int r8 = 0; r8 < 8; ++r8) {
            const int r = rg * 8 + r8;
            float4 n = *reinterpret_cast<const float4*>(&Ng[r * H_ + d]);
            float4 s = *reinterpret_cast<const float4*>(&Sf[r * H_ + d]);
            acc[r8] += n.x * wn0_ + n.y * wn1_ + n.z * wn2_ + n.w * wn3_
                     + s.x * ws0_ + s.y * ws1_ + s.z * ws2_ + s.w * ws3_;
        }
    }
#pragma unroll
    for (int r8 = 0; r8 < 8; ++r8)
        out_u[(size_t)(base + rg * 8 + r8) * C_ + c] = acc[r8];
}

// ---------------------------------------------------------------------------
// K4: edge scores (8192 edges)
// ---------------------------------------------------------------------------
__global__ __launch_bounds__(256) void k4_edges(const float* __restrict__ out_u,
                                                const int* __restrict__ rmap,
                                                const float* __restrict__ Wp1,
                                                const float* __restrict__ bp1,
                                                const float* __restrict__ Wp2,
                                                const float* __restrict__ bp2,
                                                float* __restrict__ scores) {
    __shared__ __align__(16) float E[32 * C_];
    const int t = threadIdx.x;
    const int base = blockIdx.x * 32;
    const int f = t & 127;
    const int half = t >> 7;

    for (int rr = 0; rr < 16; ++rr) {
        const int row = rr * 2 + half;
        const int j = base + row;
        const int si = rmap[j & (IC_ - 1)];
        const int di = rmap[IC_ + j];
        E[row * C_ + f] = out_u[(size_t)si * C_ + f] * out_u[(size_t)di * C_ + f];
    }
    __syncthreads();

    float acc[16];
    const float bias = bp1[f];
#pragma unroll
    for (int r16 = 0; r16 < 16; ++r16) acc[r16] = bias;

    for (int d4 = 0; d4 < C_ / 4; ++d4) {
        const int d = d4 * 4;
        const float w0 = Wp1[(d + 0) * C_ + f];
        const float w1 = Wp1[(d + 1) * C_ + f];
        const float w2 = Wp1[(d + 2) * C_ + f];
        const float w3 = Wp1[(d + 3) * C_ + f];
#pragma unroll
        for (int r16 = 0; r16 < 16; ++r16) {
            const int r = half * 16 + r16;
            float4 e4 = *reinterpret_cast<const float4*>(&E[r * C_ + d]);
            acc[r16] += e4.x * w0 + e4.y * w1 + e4.z * w2 + e4.w * w3;
        }
    }
    __syncthreads();
#pragma unroll
    for (int r16 = 0; r16 < 16; ++r16) {
        float v = acc[r16];
        E[(half * 16 + r16) * C_ + f] = v > 0.f ? v : 0.f;
    }
    __syncthreads();

    const int r = t >> 3;
    const int s = t & 7;
    float p = 0.f;
#pragma unroll
    for (int k4 = 0; k4 < 4; ++k4) {
        float4 tv = *reinterpret_cast<const float4*>(&E[r * C_ + s * 16 + k4 * 4]);
        float4 wv = *reinterpret_cast<const float4*>(&Wp2[s * 16 + k4 * 4]);
        p += tv.x * wv.x + tv.y * wv.y + tv.z * wv.z + tv.w * wv.w;
    }
    p += __shfl_down(p, 4, 8);
    p += __shfl_down(p, 2, 8);
    p += __shfl_down(p, 1, 8);
    if (s == 0) scores[base + r] = p + bp2[0];
}

// ---------------------------------------------------------------------------
extern "C" void kernel_launch(void* const* d_in, const int* in_sizes, int n_in,
                              void* d_out, int out_size, void* d_ws, size_t ws_size,
                              hipStream_t stream) {
    const float* xf   = (const float*)d_in[0];
    const float* Wn0  = (const float*)d_in[1];
    const float* Ws0  = (const float*)d_in[2];
    const float* b0   = (const float*)d_in[3];
    const float* Wn1  = (const float*)d_in[4];
    const float* Ws1  = (const float*)d_in[5];
    const float* b1   = (const float*)d_in[6];
    const float* Wp1  = (const float*)d_in[7];
    const float* bp1  = (const float*)d_in[8];
    const float* Wp2  = (const float*)d_in[9];
    const float* bp2  = (const float*)d_in[10];
    const int*   col0 = (const int*)d_in[11];
    const int*   col1 = (const int*)d_in[12];
    const int*   rmap = (const int*)d_in[13];

    // workspace layout
    char* ws = (char*)d_ws;
    float*  h     = (float*)ws;                                 // T0*256 f32 = 138.4 MB
    float*  out_u = h + (size_t)T0_ * H_;                       // T1*128 f32 = 6.3 MB
    ushort* Wpk   = (ushort*)(out_u + (size_t)T1_ * C_);        // 512 KB
    unsigned char* flag = (unsigned char*)(Wpk + (size_t)16 * 8 * 2 * 64 * 8); // T0 bytes
    float*  scores = (float*)d_out;

    hipLaunchKernelGGL(bz_zero, dim3((T0_ / 4 + 255) / 256), dim3(256), 0, stream,
                       (unsigned int*)flag);
    hipLaunchKernelGGL(bs_set, dim3((T1_ * F1_ + 255) / 256), dim3(256), 0, stream,
                       col1, flag);
    hipLaunchKernelGGL(k0_packW, dim3(16), dim3(256), 0, stream, Wn0, Ws0, Wpk);
    hipLaunchKernelGGL(k12_fused, dim3(T0_ / 64), dim3(256), 0, stream,
                       xf, col0, Wpk, b0, flag, h);
    hipLaunchKernelGGL(k3_layer1, dim3(T1_ / 16), dim3(256), 0, stream,
                       h, col1, Wn1, Ws1, b1, out_u);
    hipLaunchKernelGGL(k4_edges, dim3((2 * IC_) / 32), dim3(256), 0, stream,
                       out_u, rmap, Wp1, bp1, Wp2, bp2, scores);
}